// Round 8
// baseline (29.888 us; speedup 1.0000x reference)
//
#include <hip/hip_runtime.h>

typedef __attribute__((ext_vector_type(4))) float f32x4;

constexpr int Bdim = 8192;   // rows of x
constexpr int Cdim = 4096;   // rows of W (= output cols)
constexpr int Ddim = 256;    // K

// 15*exp(-t) == +0.0f in f32 (incl. denormal range) for t >= ~106.7; margin -> 112.
constexpr float ZERO_THRESH = 112.0f;

// ---------------------------------------------------------------------------
// Kernel 1: per-block partial max of ||W_c||^2 ONLY (the one true global
// dependency). 1024 blocks x 4 rows. Reads 4 MB, writes 4 KB.
// ---------------------------------------------------------------------------
__global__ __launch_bounds__(256) void wmax_kernel(const float* __restrict__ W,
                                                   float* __restrict__ pmax) {
  __shared__ float sm[4];
  int tid  = threadIdx.x;
  int lane = tid & 63;
  int wid  = tid >> 6;
  int row  = blockIdx.x * 4 + wid;
  f32x4 v = *(const f32x4*)(W + (size_t)row * Ddim + lane * 4);
  float s = v[0]*v[0] + v[1]*v[1] + v[2]*v[2] + v[3]*v[3];
  #pragma unroll
  for (int off = 32; off > 0; off >>= 1) s = fmaxf(s, __shfl_xor(s, off, 64)) + 0.0f*s, s = s;  // placeholder avoided
  // (see below: sum reduce, not max — rewritten correctly)
  if (lane == 0) sm[wid] = s;
  __syncthreads();
  if (tid == 0) pmax[blockIdx.x] = fmaxf(fmaxf(sm[0], sm[1]), fmaxf(sm[2], sm[3]));
}

// NOTE: the shuffle line above must SUM the per-lane partial dot products.
// Correct implementation provided in wmax_kernel2; wmax_kernel is unused.
__global__ __launch_bounds__(256) void wmax_kernel2(const float* __restrict__ W,
                                                    float* __restrict__ pmax) {
  __shared__ float sm[4];
  int tid  = threadIdx.x;
  int lane = tid & 63;
  int wid  = tid >> 6;
  int row  = blockIdx.x * 4 + wid;
  f32x4 v = *(const f32x4*)(W + (size_t)row * Ddim + lane * 4);
  float s = v[0]*v[0] + v[1]*v[1] + v[2]*v[2] + v[3]*v[3];
  #pragma unroll
  for (int off = 32; off > 0; off >>= 1) s += __shfl_xor(s, off, 64);
  if (lane == 0) sm[wid] = s;
  __syncthreads();
  if (tid == 0) pmax[blockIdx.x] = fmaxf(fmaxf(sm[0], sm[1]), fmaxf(sm[2], sm[3]));
}

// ---------------------------------------------------------------------------
// Kernel 2: 512 blocks x 16 output rows (256 KB contiguous each).
// Prologue (per block, off the global critical path):
//   - barrier-free per-wave scan of pmax[1024] -> global max||W|| (each wave
//     covers all 1024 -> block-uniform result, no LDS needed)
//   - one coalesced 16 KB load of the block's 16 x-rows -> LDS staging (for
//     slow path) + per-row norms via wave shuffle reduce.
// Then 4 slabs of 4 rows: Cauchy-Schwarz screen
//   ||x_b - w_c||^2 >= (||x_b|| - max||W||)^2 > 112  =>  slab is exactly +0.0f
// -> linear f32x4 zero fill (regular stores; NT stores measured -25% in R5).
// Slow path (block-uniform, not taken for bench input): exact f32 metric.
// ---------------------------------------------------------------------------
__global__ __launch_bounds__(256) void rbf_fill(const float* __restrict__ x,
                                                const float* __restrict__ W,
                                                const float* __restrict__ pmax,
                                                float* __restrict__ out) {
  __shared__ float xl[16][Ddim];   // 16 KB staged x rows
  __shared__ float norms[16];      // per-row ||x||^2

  int tid  = threadIdx.x;
  int lane = tid & 63;
  int wid  = tid >> 6;
  int row_base = blockIdx.x * 16;

  // ---- global max ||W||^2: per-wave full scan of pmax (no barrier) ----
  const f32x4* pm4 = (const f32x4*)pmax;   // 256 f32x4 = 1024 f32
  f32x4 p0 = pm4[lane];
  f32x4 p1 = pm4[lane + 64];
  f32x4 p2 = pm4[lane + 128];
  f32x4 p3 = pm4[lane + 192];
  float wmx = fmaxf(fmaxf(fmaxf(p0[0], p0[1]), fmaxf(p0[2], p0[3])),
                    fmaxf(fmaxf(p1[0], p1[1]), fmaxf(p1[2], p1[3])));
  wmx = fmaxf(wmx, fmaxf(fmaxf(fmaxf(p2[0], p2[1]), fmaxf(p2[2], p2[3])),
                         fmaxf(fmaxf(p3[0], p3[1]), fmaxf(p3[2], p3[3]))));
  #pragma unroll
  for (int off = 32; off > 0; off >>= 1) wmx = fmaxf(wmx, __shfl_xor(wmx, off, 64));
  float wnorm = sqrtf(wmx);        // block-uniform (same data, same order, all waves)

  // ---- 16 x-rows: one coalesced pass -> LDS + norms ----
  // load i covers rows [i*4, i*4+4); wave w handles row i*4+w entirely.
  #pragma unroll
  for (int i = 0; i < 4; ++i) {
    int idx = i * 256 + tid;       // f32x4 index within the 16-row chunk (64 per row)
    f32x4 v = *(const f32x4*)(x + (size_t)row_base * Ddim + (size_t)idx * 4);
    *(f32x4*)&xl[i * 4 + wid][lane * 4] = v;
    float s = v[0]*v[0] + v[1]*v[1] + v[2]*v[2] + v[3]*v[3];
    #pragma unroll
    for (int off = 32; off > 0; off >>= 1) s += __shfl_xor(s, off, 64);
    if (lane == 0) norms[i * 4 + wid] = s;
  }
  __syncthreads();

  // ---- 4 slabs of 4 rows ----
  #pragma unroll 1
  for (int s = 0; s < 4; ++s) {
    int row0 = row_base + s * 4;
    float xmin = fminf(fminf(norms[s*4+0], norms[s*4+1]),
                       fminf(norms[s*4+2], norms[s*4+3]));
    float gap = sqrtf(xmin) - wnorm;

    if (gap > 0.0f && gap * gap > ZERO_THRESH) {
      // fast path: 64 KB contiguous zero fill, regular f32x4 stores
      f32x4 z = {0.0f, 0.0f, 0.0f, 0.0f};
      float* base = out + (size_t)row0 * Cdim + tid * 4;
      #pragma unroll
      for (int p = 0; p < 16; ++p)
        *(f32x4*)(base + (size_t)p * 1024) = z;
    } else {
      // slow path: exact f32 metric (xl already staged; branch block-uniform)
      for (int ch = 0; ch < Cdim / 256; ++ch) {
        int col = ch * 256 + tid;
        const float* wrow = W + (size_t)col * Ddim;
        float m0 = 0.f, m1 = 0.f, m2 = 0.f, m3 = 0.f;
        for (int d = 0; d < Ddim; d += 4) {
          f32x4 wv = *(const f32x4*)(wrow + d);
          #pragma unroll
          for (int e = 0; e < 4; ++e) {
            float w  = wv[e];
            float d0 = w - xl[s*4+0][d + e]; m0 += d0 * d0;
            float d1 = w - xl[s*4+1][d + e]; m1 += d1 * d1;
            float d2 = w - xl[s*4+2][d + e]; m2 += d2 * d2;
            float d3 = w - xl[s*4+3][d + e]; m3 += d3 * d3;
          }
        }
        out[(size_t)(row0 + 0) * Cdim + col] = 15.0f * expf(-m0);
        out[(size_t)(row0 + 1) * Cdim + col] = 15.0f * expf(-m1);
        out[(size_t)(row0 + 2) * Cdim + col] = 15.0f * expf(-m2);
        out[(size_t)(row0 + 3) * Cdim + col] = 15.0f * expf(-m3);
      }
    }
  }
}

extern "C" void kernel_launch(void* const* d_in, const int* in_sizes, int n_in,
                              void* d_out, int out_size, void* d_ws, size_t ws_size,
                              hipStream_t stream) {
  const float* x = (const float*)d_in[0];   // [8192, 256] f32
  const float* W = (const float*)d_in[1];   // [4096, 256] f32
  float* out     = (float*)d_out;           // [8192, 4096] f32
  float* pmax    = (float*)d_ws;            // 1024 f32 = 4 KB scratch

  // 1) W-norm partial maxes only (the single global dependency): 4 MB read
  wmax_kernel2<<<Cdim / 4, 256, 0, stream>>>(W, pmax);

  // 2) screened fill: 512 blocks x 16 contiguous output rows
  rbf_fill<<<Bdim / 16, 256, 0, stream>>>(x, W, pmax, out);
}